// Round 1
// baseline (122.354 us; speedup 1.0000x reference)
//
#include <hip/hip_runtime.h>
#include <math.h>

// Sizes (fixed per reference)
#define H    2048
#define UDIM 1024
#define DUD  256
#define UD   1280   // DU + U, du first
#define YD   1024
#define NTAYLOR 6   // matvec iterations; trunc err ~ (0.082)^7/7! ~ 5e-12 rel

// ws layout in floats. Requires ws_size >= (H*H + 6*H)*4 bytes ~= 16.9 MB.
#define OFF_A    0
#define OFF_XH0  (H*H)
#define OFF_XH1  (OFF_XH0 + H)
#define OFF_XB0  (OFF_XH1 + H)
#define OFF_XB1  (OFF_XB0 + H)
#define OFF_S1   (OFF_XB1 + H)
#define OFF_S2   (OFF_S1 + H)

// ---------------------------------------------------------------------------
// A = 0.5*(W - W^T), 64x64 tile pairs (ti<=tj), one read of W, one write of A.
__global__ __launch_bounds__(256) void build_A(const float* __restrict__ W,
                                               float* __restrict__ A) {
    // decode triangular pair index -> (ti, tj), ti <= tj, 32x32 tiles
    int p = blockIdx.x;
    int ti = 0, rowlen = H / 64;
    while (p >= rowlen) { p -= rowlen; ++ti; --rowlen; }
    int tj = ti + p;

    __shared__ float t1[64][65];
    __shared__ float t2[64][65];
    const int tx = threadIdx.x & 63, ty = threadIdx.x >> 6;
    const int r0 = ti * 64, c0 = tj * 64;

    for (int r = ty; r < 64; r += 4) {
        t1[r][tx] = W[(size_t)(r0 + r) * H + c0 + tx];
        t2[r][tx] = W[(size_t)(c0 + r) * H + r0 + tx];
    }
    __syncthreads();
    for (int r = ty; r < 64; r += 4) {
        A[(size_t)(r0 + r) * H + c0 + tx] = 0.5f * (t1[r][tx] - t2[tx][r]);
        if (ti != tj)
            A[(size_t)(c0 + r) * H + r0 + tx] = 0.5f * (t2[r][tx] - t1[tx][r]);
    }
}

// ---------------------------------------------------------------------------
// bu = B @ [du, u]; init chains: xh0=s1=h, xb0=s2=0.1*bu  (q0 = DELTA*bu)
__global__ __launch_bounds__(256) void bu_init(const float* __restrict__ Bw,
                                               const float* __restrict__ u,
                                               const float* __restrict__ du,
                                               const float* __restrict__ h,
                                               float* __restrict__ ws) {
    float* xh0 = ws + OFF_XH0;
    float* xb0 = ws + OFF_XB0;
    float* s1  = ws + OFF_S1;
    float* s2  = ws + OFF_S2;

    const int gt = blockIdx.x * 256 + threadIdx.x;
    if (gt < H) { float hv = h[gt]; xh0[gt] = hv; s1[gt] = hv; }

    const int w = gt >> 6;      // wave id 0..1023
    const int lane = gt & 63;

    // udu fragments: float4 index f in [0,320); f<64 -> du, else u
    float4 xv[5];
    #pragma unroll
    for (int i = 0; i < 5; ++i) {
        int f = i * 64 + lane;
        xv[i] = (f < 64) ? ((const float4*)du)[f] : ((const float4*)u)[f - 64];
    }
    #pragma unroll
    for (int rr = 0; rr < 2; ++rr) {
        int r = w * 2 + rr;
        const float4* Brow = (const float4*)(Bw + (size_t)r * UD);
        float acc = 0.f;
        #pragma unroll
        for (int i = 0; i < 5; ++i) {
            float4 b = Brow[i * 64 + lane];
            acc = fmaf(b.x, xv[i].x, acc);
            acc = fmaf(b.y, xv[i].y, acc);
            acc = fmaf(b.z, xv[i].z, acc);
            acc = fmaf(b.w, xv[i].w, acc);
        }
        #pragma unroll
        for (int off = 32; off; off >>= 1) acc += __shfl_xor(acc, off, 64);
        if (lane == 0) { float v = 0.1f * acc; xb0[r] = v; s2[r] = v; }
    }
}

// ---------------------------------------------------------------------------
// Dual-chain matvec: yh = A xh_in, yb = A xb_in; x_out = c*y; s += x_out.
// Wave per 2 rows; x fragments hoisted to registers (shared by both rows).
__global__ __launch_bounds__(256) void matvec(const float* __restrict__ A,
                                              const float4* __restrict__ xhin,
                                              const float4* __restrict__ xbin,
                                              float* __restrict__ xhout,
                                              float* __restrict__ xbout,
                                              float* __restrict__ s1,
                                              float* __restrict__ s2,
                                              float cH, float cB) {
    const int gt = blockIdx.x * 256 + threadIdx.x;
    const int w = gt >> 6, lane = gt & 63;

    float4 xh[8], xb[8];
    #pragma unroll
    for (int i = 0; i < 8; ++i) {
        int f = i * 64 + lane;
        xh[i] = xhin[f];
        xb[i] = xbin[f];
    }
    #pragma unroll
    for (int rr = 0; rr < 2; ++rr) {
        int r = w * 2 + rr;
        const float4* Arow = (const float4*)(A + (size_t)r * H);
        float ah = 0.f, ab = 0.f;
        #pragma unroll
        for (int i = 0; i < 8; ++i) {
            float4 a = Arow[i * 64 + lane];
            ah = fmaf(a.x, xh[i].x, ah); ab = fmaf(a.x, xb[i].x, ab);
            ah = fmaf(a.y, xh[i].y, ah); ab = fmaf(a.y, xb[i].y, ab);
            ah = fmaf(a.z, xh[i].z, ah); ab = fmaf(a.z, xb[i].z, ab);
            ah = fmaf(a.w, xh[i].w, ah); ab = fmaf(a.w, xb[i].w, ab);
        }
        #pragma unroll
        for (int off = 32; off; off >>= 1) {
            ah += __shfl_xor(ah, off, 64);
            ab += __shfl_xor(ab, off, 64);
        }
        if (lane == 0) {
            float nh = cH * ah, nb = cB * ab;
            xhout[r] = nh; xbout[r] = nb;
            s1[r] += nh;   s2[r] += nb;   // only this lane touches row r
        }
    }
}

// ---------------------------------------------------------------------------
// y = C @ (s1 + s2); wave per output row (1024 rows == 1024 waves)
__global__ __launch_bounds__(256) void final_y(const float* __restrict__ C,
                                               const float* __restrict__ ws,
                                               float* __restrict__ out) {
    const float4* s14 = (const float4*)(ws + OFF_S1);
    const float4* s24 = (const float4*)(ws + OFF_S2);
    const int gt = blockIdx.x * 256 + threadIdx.x;
    const int w = gt >> 6, lane = gt & 63;   // w == output row

    float4 hx[8];
    #pragma unroll
    for (int i = 0; i < 8; ++i) {
        int f = i * 64 + lane;
        float4 a = s14[f], b = s24[f];
        hx[i] = make_float4(a.x + b.x, a.y + b.y, a.z + b.z, a.w + b.w);
    }
    const float4* Crow = (const float4*)(C + (size_t)w * H);
    float acc = 0.f;
    #pragma unroll
    for (int i = 0; i < 8; ++i) {
        float4 c = Crow[i * 64 + lane];
        acc = fmaf(c.x, hx[i].x, acc);
        acc = fmaf(c.y, hx[i].y, acc);
        acc = fmaf(c.z, hx[i].z, acc);
        acc = fmaf(c.w, hx[i].w, acc);
    }
    #pragma unroll
    for (int off = 32; off; off >>= 1) acc += __shfl_xor(acc, off, 64);
    if (lane == 0) out[w] = acc;
}

// ---------------------------------------------------------------------------
extern "C" void kernel_launch(void* const* d_in, const int* in_sizes, int n_in,
                              void* d_out, int out_size, void* d_ws, size_t ws_size,
                              hipStream_t stream) {
    const float* u  = (const float*)d_in[0];
    const float* du = (const float*)d_in[1];
    const float* W  = (const float*)d_in[2];
    const float* Bw = (const float*)d_in[3];
    const float* Cw = (const float*)d_in[4];
    const float* h  = (const float*)d_in[5];
    float* ws  = (float*)d_ws;
    float* out = (float*)d_out;

    // A = 0.5*(W - W^T): 528 tile-pair blocks (32x32 tiles of 64x64)
    build_A<<<528, 256, 0, stream>>>(W, ws + OFF_A);
    // bu + chain init
    bu_init<<<256, 256, 0, stream>>>(Bw, u, du, h, ws);

    float* xh[2] = {ws + OFF_XH0, ws + OFF_XH1};
    float* xb[2] = {ws + OFF_XB0, ws + OFF_XB1};
    for (int k = 0; k < NTAYLOR; ++k) {
        int a = k & 1, b = a ^ 1;
        matvec<<<256, 256, 0, stream>>>(ws + OFF_A,
                                        (const float4*)xh[a], (const float4*)xb[a],
                                        xh[b], xb[b],
                                        ws + OFF_S1, ws + OFF_S2,
                                        0.1f / (float)(k + 1), 0.1f / (float)(k + 2));
    }
    final_y<<<256, 256, 0, stream>>>(Cw, ws, out);
}

// Round 3
// 109.280 us; speedup vs baseline: 1.1196x; 1.1196x over previous
//
#include <hip/hip_runtime.h>
#include <math.h>

// Sizes (fixed per reference)
#define H    2048
#define UDIM 1024
#define DUD  256
#define UD   1280   // DU + U concat, du first
#define YD   1024
#define NTAYLOR 4   // ||0.1*A||_2 ~ 0.082 -> trunc err ~0.082^5/5! ~ 3e-8 rel

// ws layout in floats. Requires ws_size >= (H*H + 6*H)*4 bytes ~= 16.9 MB.
#define OFF_A    0
#define OFF_XH0  (H*H)
#define OFF_XH1  (OFF_XH0 + H)
#define OFF_XB0  (OFF_XH1 + H)
#define OFF_XB1  (OFF_XB0 + H)
#define OFF_S1   (OFF_XB1 + H)
#define OFF_S2   (OFF_S1 + H)

#define NTILE       (H / 64)                 // 32
#define NPAIRS      (NTILE * (NTILE + 1) / 2) // 528 A-tile-pair blocks
#define BU_BLOCKS   512                      // wave per row of B (2048 rows)

// ---------------------------------------------------------------------------
// Fused: blocks [0,528) build A = 0.5*(W - W^T) (64x64 tile pairs);
// blocks [528, 528+512) compute bu = B@[du,u], init chains.
__global__ __launch_bounds__(256) void build_init(const float* __restrict__ W,
                                                  const float* __restrict__ Bw,
                                                  const float* __restrict__ u,
                                                  const float* __restrict__ du,
                                                  const float* __restrict__ h,
                                                  float* __restrict__ ws) {
    if (blockIdx.x < NPAIRS) {
        float* A = ws + OFF_A;
        // decode triangular pair index -> (ti, tj), ti <= tj
        int p = blockIdx.x;
        int ti = 0, rowlen = NTILE;
        while (p >= rowlen) { p -= rowlen; ++ti; --rowlen; }
        int tj = ti + p;

        __shared__ float t1[64][65];
        __shared__ float t2[64][65];
        const int tx = threadIdx.x & 63, ty = threadIdx.x >> 6;
        const int r0 = ti * 64, c0 = tj * 64;

        for (int r = ty; r < 64; r += 4) {
            t1[r][tx] = W[(size_t)(r0 + r) * H + c0 + tx];
            t2[r][tx] = W[(size_t)(c0 + r) * H + r0 + tx];
        }
        __syncthreads();
        for (int r = ty; r < 64; r += 4) {
            A[(size_t)(r0 + r) * H + c0 + tx] = 0.5f * (t1[r][tx] - t2[tx][r]);
            if (ti != tj)
                A[(size_t)(c0 + r) * H + r0 + tx] = 0.5f * (t2[r][tx] - t1[tx][r]);
        }
    } else {
        // bu-init half: wave per row of B
        float* xh0 = ws + OFF_XH0;
        float* xb0 = ws + OFF_XB0;
        float* s1  = ws + OFF_S1;
        float* s2  = ws + OFF_S2;

        const int bid = blockIdx.x - NPAIRS;              // [0,512)
        const int gt  = bid * 256 + threadIdx.x;          // [0,131072)
        const int lane = threadIdx.x & 63;
        const int r = bid * 4 + (threadIdx.x >> 6);       // row of B, [0,2048)

        if (gt < H) { float hv = h[gt]; xh0[gt] = hv; s1[gt] = hv; }

        // udu fragments: float4 index f in [0,320); f<64 -> du, else u
        const float4* Brow = (const float4*)(Bw + (size_t)r * UD);
        float acc = 0.f;
        #pragma unroll
        for (int i = 0; i < 5; ++i) {
            int f = i * 64 + lane;
            float4 xv = (f < 64) ? ((const float4*)du)[f] : ((const float4*)u)[f - 64];
            float4 b = Brow[f];
            acc = fmaf(b.x, xv.x, acc);
            acc = fmaf(b.y, xv.y, acc);
            acc = fmaf(b.z, xv.z, acc);
            acc = fmaf(b.w, xv.w, acc);
        }
        #pragma unroll
        for (int off = 32; off; off >>= 1) acc += __shfl_xor(acc, off, 64);
        if (lane == 0) { float v = 0.1f * acc; xb0[r] = v; s2[r] = v; }
    }
}

// ---------------------------------------------------------------------------
// Dual-chain matvec: yh = A xh_in, yb = A xb_in; x_out = c*y; s += x_out.
// Block = 4 waves handles 2 rows; each wave does (row, K-half); LDS combine.
// Grid 1024 blocks -> 4 blocks/CU, 4 waves/SIMD.
__global__ __launch_bounds__(256) void matvec(const float* __restrict__ A,
                                              const float4* __restrict__ xhin,
                                              const float4* __restrict__ xbin,
                                              float* __restrict__ xhout,
                                              float* __restrict__ xbout,
                                              float* __restrict__ s1,
                                              float* __restrict__ s2,
                                              float cH, float cB) {
    const int tid  = threadIdx.x;
    const int lane = tid & 63;
    const int w    = tid >> 6;        // wave in block, 0..3
    const int rl   = w >> 1;          // local row 0..1
    const int hf   = w & 1;           // K-half 0..1
    const int r    = blockIdx.x * 2 + rl;

    const float4* Arow = (const float4*)(A + (size_t)r * H);
    float ah = 0.f, ab = 0.f;
    #pragma unroll
    for (int i = 0; i < 4; ++i) {
        int f = hf * 256 + i * 64 + lane;     // float4 index into row / x
        float4 a  = Arow[f];
        float4 xh = xhin[f];
        float4 xb = xbin[f];
        ah = fmaf(a.x, xh.x, ah); ab = fmaf(a.x, xb.x, ab);
        ah = fmaf(a.y, xh.y, ah); ab = fmaf(a.y, xb.y, ab);
        ah = fmaf(a.z, xh.z, ah); ab = fmaf(a.z, xb.z, ab);
        ah = fmaf(a.w, xh.w, ah); ab = fmaf(a.w, xb.w, ab);
    }
    #pragma unroll
    for (int off = 32; off; off >>= 1) {
        ah += __shfl_xor(ah, off, 64);
        ab += __shfl_xor(ab, off, 64);
    }

    __shared__ float ph[4], pb[4];
    if (lane == 0) { ph[w] = ah; pb[w] = ab; }
    __syncthreads();
    if (tid < 2) {                    // tid == local row
        int rr = blockIdx.x * 2 + tid;
        float nh = cH * (ph[tid * 2] + ph[tid * 2 + 1]);
        float nb = cB * (pb[tid * 2] + pb[tid * 2 + 1]);
        xhout[rr] = nh; xbout[rr] = nb;
        s1[rr] += nh;   s2[rr] += nb;   // exclusive owner of row rr
    }
}

// ---------------------------------------------------------------------------
// y = C @ (s1 + s2); block = 4 waves, 2 rows, K-half per wave. 512 blocks.
__global__ __launch_bounds__(256) void final_y(const float* __restrict__ C,
                                               const float* __restrict__ ws,
                                               float* __restrict__ out) {
    const float4* s14 = (const float4*)(ws + OFF_S1);
    const float4* s24 = (const float4*)(ws + OFF_S2);
    const int tid  = threadIdx.x;
    const int lane = tid & 63;
    const int w    = tid >> 6;
    const int rl   = w >> 1;
    const int hf   = w & 1;
    const int r    = blockIdx.x * 2 + rl;

    const float4* Crow = (const float4*)(C + (size_t)r * H);
    float acc = 0.f;
    #pragma unroll
    for (int i = 0; i < 4; ++i) {
        int f = hf * 256 + i * 64 + lane;
        float4 c = Crow[f];
        float4 a = s14[f], b = s24[f];
        acc = fmaf(c.x, a.x + b.x, acc);
        acc = fmaf(c.y, a.y + b.y, acc);
        acc = fmaf(c.z, a.z + b.z, acc);
        acc = fmaf(c.w, a.w + b.w, acc);
    }
    #pragma unroll
    for (int off = 32; off; off >>= 1) acc += __shfl_xor(acc, off, 64);

    __shared__ float pr[4];
    if (lane == 0) pr[w] = acc;
    __syncthreads();
    if (tid < 2) out[blockIdx.x * 2 + tid] = pr[tid * 2] + pr[tid * 2 + 1];
}

// ---------------------------------------------------------------------------
extern "C" void kernel_launch(void* const* d_in, const int* in_sizes, int n_in,
                              void* d_out, int out_size, void* d_ws, size_t ws_size,
                              hipStream_t stream) {
    const float* u  = (const float*)d_in[0];
    const float* du = (const float*)d_in[1];
    const float* W  = (const float*)d_in[2];
    const float* Bw = (const float*)d_in[3];
    const float* Cw = (const float*)d_in[4];
    const float* h  = (const float*)d_in[5];
    float* ws  = (float*)d_ws;
    float* out = (float*)d_out;

    build_init<<<NPAIRS + BU_BLOCKS, 256, 0, stream>>>(W, Bw, u, du, h, ws);

    float* xh[2] = {ws + OFF_XH0, ws + OFF_XH1};
    float* xb[2] = {ws + OFF_XB0, ws + OFF_XB1};
    for (int k = 0; k < NTAYLOR; ++k) {
        int a = k & 1, b = a ^ 1;
        matvec<<<1024, 256, 0, stream>>>(ws + OFF_A,
                                         (const float4*)xh[a], (const float4*)xb[a],
                                         xh[b], xb[b],
                                         ws + OFF_S1, ws + OFF_S2,
                                         0.1f / (float)(k + 1), 0.1f / (float)(k + 2));
    }
    final_y<<<512, 256, 0, stream>>>(Cw, ws, out);
}